// Round 1
// baseline (373.605 us; speedup 1.0000x reference)
//
#include <hip/hip_runtime.h>
#include <math.h>

// Fused LSTM (Keras gates i,f,c~,o; act=relu, rec_act=sigmoid) + Dense(64,sigmoid)
// + row-sum normalize.  B=4096, T=256, F=64, H=16, 4H=64, D=64, fp32 in/out.
//
// One wave64 per FOUR batch rows; 16 lanes per row, lane = unit k, all four
// gates of unit k in-lane (float2 packs -> v_pk_fma_f32).
//
// Round-6 change: the recurrence serial chain previously contained an LDS
// store->waitcnt->load round trip for the h broadcast PLUS a per-step compiler
// memory barrier that serialized every xwbuf read.  Both are gone:
//   - h broadcast is now a single-hop ds_bpermute all-gather (h stays in VGPRs,
//     16 independent bpermutes, one lgkmcnt wait ~= one LDS-pipe latency).
//   - all 16 xw float4s are hoisted to registers once per chunk, so the
//     16-step t-loop touches no memory at all and has no barriers.
//
// Precision: unchanged error-compensated f16 split for x@W (hi*hi+lo*hi+hi*lo
// into one fp32 MFMA accumulator); recurrence math identical to the version
// that measured absmax 6.1e-5.

#define T_STEPS 256
#define F_DIM   64
#define ROW_ELEMS (T_STEPS * F_DIM)      // 16384

typedef _Float16 h8  __attribute__((ext_vector_type(8)));   // MFMA operand (4 VGPRs)
typedef float    f4v __attribute__((ext_vector_type(4)));
typedef float    f2v __attribute__((ext_vector_type(2)));

union H8s { h8 v; _Float16 e[8]; };

__device__ __forceinline__ float fast_sigmoid(float z) {
    return __builtin_amdgcn_rcpf(1.0f + __expf(-z));
}

// single-hop cross-lane gather: dst lane gets src-lane (byte_addr>>2)'s value
__device__ __forceinline__ float bperm_f(int byte_addr, float v) {
    return __int_as_float(__builtin_amdgcn_ds_bpermute(byte_addr, __float_as_int(v)));
}

// split one float4 into f16 hi + f16 lo fragments (elements o..o+3)
__device__ __forceinline__ void split4(const float4 v, H8s& hi, H8s& lo, int o) {
    const float f[4] = {v.x, v.y, v.z, v.w};
    #pragma unroll
    for (int i = 0; i < 4; ++i) {
        const _Float16 h = (_Float16)f[i];            // RTE
        hi.e[o + i] = h;
        lo.e[o + i] = (_Float16)(f[i] - (float)h);    // residual exact in fp32
    }
}

__global__ __launch_bounds__(64, 1)
void lstm_fused_kernel(const float* __restrict__ x,
                       const float* __restrict__ W,
                       const float* __restrict__ U,
                       const float* __restrict__ bias,
                       const float* __restrict__ Wd,
                       const float* __restrict__ bd,
                       float* __restrict__ out)
{
    __shared__ float4 xwbuf[4][16][16];   // [row][t][unit] = (zi,zf,zg,zo)  16 KB

    const int lane = threadIdx.x;        // block = 1 wave
    const int k    = lane & 15;          // unit; MFMA B-col n; C col
    const int q    = lane >> 4;          // MFMA k-group; C row group; recurrence row
    const int b0   = blockIdx.x * 4;
    const int baddr = (lane & 48) << 2;  // q*16*4 : bpermute base (bytes)

    // ---- W as hi/lo f16 MFMA B-fragments (layout validated in prior rounds).
    // B[kdim][n]: n = tt*16+k slice col, kdim = cc*32 + q*8 + j.
    h8 Whi[8], Wlo[8];
    #pragma unroll
    for (int tt = 0; tt < 4; ++tt) {
        const int col = tt * 16 + k;
        #pragma unroll
        for (int cc = 0; cc < 2; ++cc) {
            H8s uh, ul;
            #pragma unroll
            for (int j = 0; j < 8; ++j) {
                const float w = W[(cc * 32 + q * 8 + j) * 64 + col];
                const _Float16 wh = (_Float16)w;
                uh.e[j] = wh;
                ul.e[j] = (_Float16)(w - (float)wh);
            }
            Whi[2 * tt + cc] = uh.v;
            Wlo[2 * tt + cc] = ul.v;
        }
    }

    // ---- recurrent weights as float2 packs: (gate k, 16+k) / (32+k, 48+k)
    f2v Uif[16], Ugo[16];
    #pragma unroll
    for (int j = 0; j < 16; ++j) {
        Uif[j] = (f2v){U[j * 64 + k],      U[j * 64 + 16 + k]};
        Ugo[j] = (f2v){U[j * 64 + 32 + k], U[j * 64 + 48 + k]};
    }
    const f2v bif = (f2v){bias[k],      bias[16 + k]};
    const f2v bgo = (f2v){bias[32 + k], bias[48 + k]};

    // ---- A-operand pointers per row + prefetch chunk 0
    const float* ap0 = x + (size_t)(b0 + 0) * ROW_ELEMS + k * F_DIM + q * 8;
    const float* ap[4] = {ap0, ap0 + ROW_ELEMS, ap0 + 2 * ROW_ELEMS, ap0 + 3 * ROW_ELEMS};

    float4 xv[4][4];
    #pragma unroll
    for (int r = 0; r < 4; ++r) {
        xv[r][0] = *(const float4*)(ap[r] + 0);
        xv[r][1] = *(const float4*)(ap[r] + 4);
        xv[r][2] = *(const float4*)(ap[r] + 32);
        xv[r][3] = *(const float4*)(ap[r] + 36);
    }

    float h = 0.0f, c = 0.0f;

    for (int ch = 0; ch < 16; ++ch) {
        // ---- xw = x@W for 4 rows (24 MFMAs each: hi*hi + lo*hi + hi*lo)
        #pragma unroll
        for (int r = 0; r < 4; ++r) {
            H8s a0h, a0l, a1h, a1l;
            split4(xv[r][0], a0h, a0l, 0);
            split4(xv[r][1], a0h, a0l, 4);
            split4(xv[r][2], a1h, a1l, 0);
            split4(xv[r][3], a1h, a1l, 4);

            f4v acc[4];
            #pragma unroll
            for (int tt = 0; tt < 4; ++tt) {
                acc[tt] = (f4v){0.0f, 0.0f, 0.0f, 0.0f};
                acc[tt] = __builtin_amdgcn_mfma_f32_16x16x32_f16(a0h.v, Whi[2 * tt],     acc[tt], 0, 0, 0);
                acc[tt] = __builtin_amdgcn_mfma_f32_16x16x32_f16(a1h.v, Whi[2 * tt + 1], acc[tt], 0, 0, 0);
                acc[tt] = __builtin_amdgcn_mfma_f32_16x16x32_f16(a0l.v, Whi[2 * tt],     acc[tt], 0, 0, 0);
                acc[tt] = __builtin_amdgcn_mfma_f32_16x16x32_f16(a1l.v, Whi[2 * tt + 1], acc[tt], 0, 0, 0);
                acc[tt] = __builtin_amdgcn_mfma_f32_16x16x32_f16(a0h.v, Wlo[2 * tt],     acc[tt], 0, 0, 0);
                acc[tt] = __builtin_amdgcn_mfma_f32_16x16x32_f16(a1h.v, Wlo[2 * tt + 1], acc[tt], 0, 0, 0);
            }
            // C layout: lane (q,k) holds C[m=q*4+r_][n in {k,16+k,32+k,48+k}]
            #pragma unroll
            for (int r_ = 0; r_ < 4; ++r_)
                xwbuf[r][q * 4 + r_][k] =
                    make_float4(acc[0][r_], acc[1][r_], acc[2][r_], acc[3][r_]);
        }
        __asm__ __volatile__("" ::: "memory");   // xwbuf writes before reads below

        // ---- prefetch next chunk (vmem, hidden under the 16 recurrence steps)
        if (ch < 15) {
            #pragma unroll
            for (int r = 0; r < 4; ++r) {
                const float* np = ap[r] + (ch + 1) * (16 * F_DIM);
                xv[r][0] = *(const float4*)(np + 0);
                xv[r][1] = *(const float4*)(np + 4);
                xv[r][2] = *(const float4*)(np + 32);
                xv[r][3] = *(const float4*)(np + 36);
            }
        }

        // ---- hoist all 16 timesteps' xw into registers: t-loop is LDS-free
        float4 xwt[16];
        #pragma unroll
        for (int t = 0; t < 16; ++t)
            xwt[t] = xwbuf[q][t][k];

        // ---- 16 recurrence steps, all-in-lane gates, single-hop h gather
        #pragma unroll
        for (int t = 0; t < 16; ++t) {
            // gather h of all 16 units of row q (src lane = q*16+j)
            float hj[16];
            #pragma unroll
            for (int j = 0; j < 16; ++j)
                hj[j] = bperm_f(baddr + 4 * j, h);

            const float4 xw4 = xwt[t];
            f2v zif  = bif + (f2v){xw4.x, xw4.y};
            f2v zgo  = bgo + (f2v){xw4.z, xw4.w};
            f2v zif2 = (f2v){0.0f, 0.0f};
            f2v zgo2 = (f2v){0.0f, 0.0f};
            #pragma unroll
            for (int j = 0; j < 16; j += 2) {
                const f2v ha = (f2v){hj[j],     hj[j]};
                const f2v hb = (f2v){hj[j + 1], hj[j + 1]};
                zif  = ha * Uif[j]     + zif;     // v_pk_fma_f32
                zgo  = ha * Ugo[j]     + zgo;
                zif2 = hb * Uif[j + 1] + zif2;
                zgo2 = hb * Ugo[j + 1] + zgo2;
            }
            zif += zif2;
            zgo += zgo2;

            const float gi = fast_sigmoid(zif.x);
            const float gf = fast_sigmoid(zif.y);
            const float gg = fmaxf(zgo.x, 0.0f);   // candidate: relu
            const float go = fast_sigmoid(zgo.y);

            c = fmaf(gf, c, gi * gg);
            h = go * fmaxf(c, 0.0f);               // h stays in-register
        }
    }

    // ---- Dense(64, sigmoid) + row-sum normalize; lane covers d = {k,16+k,32+k,48+k}
    float hj[16];
    #pragma unroll
    for (int j = 0; j < 16; ++j)
        hj[j] = bperm_f(baddr + 4 * j, h);

    f2v aif = (f2v){bd[k],      bd[16 + k]};
    f2v ago = (f2v){bd[32 + k], bd[48 + k]};
    #pragma unroll
    for (int j = 0; j < 16; ++j) {
        const f2v wif = (f2v){Wd[j * 64 + k],      Wd[j * 64 + 16 + k]};
        const f2v wgo = (f2v){Wd[j * 64 + 32 + k], Wd[j * 64 + 48 + k]};
        const f2v hjj = (f2v){hj[j], hj[j]};
        aif = hjj * wif + aif;
        ago = hjj * wgo + ago;
    }
    const float o0 = fast_sigmoid(aif.x);
    const float o1 = fast_sigmoid(aif.y);
    const float o2 = fast_sigmoid(ago.x);
    const float o3 = fast_sigmoid(ago.y);

    float s = o0 + o1 + o2 + o3;
    s += __shfl_xor(s, 1);
    s += __shfl_xor(s, 2);
    s += __shfl_xor(s, 4);
    s += __shfl_xor(s, 8);
    const float rs = __builtin_amdgcn_rcpf(s);

    float* orow = out + (size_t)(b0 + q) * 64;
    orow[k]      = o0 * rs;
    orow[16 + k] = o1 * rs;
    orow[32 + k] = o2 * rs;
    orow[48 + k] = o3 * rs;
}

extern "C" void kernel_launch(void* const* d_in, const int* in_sizes, int n_in,
                              void* d_out, int out_size, void* d_ws, size_t ws_size,
                              hipStream_t stream) {
    const float* x    = (const float*)d_in[0];   // [4096, 256, 64]
    const float* W    = (const float*)d_in[1];   // [64, 64]
    const float* U    = (const float*)d_in[2];   // [16, 64]
    const float* bias = (const float*)d_in[3];   // [64]
    const float* Wd   = (const float*)d_in[4];   // [16, 64]
    const float* bd   = (const float*)d_in[5];   // [64]
    float* out        = (float*)d_out;           // [4096, 64]

    const int n_rows = in_sizes[0] / ROW_ELEMS;  // 4096
    dim3 grid(n_rows / 4), block(64);            // 1024 single-wave blocks
    lstm_fused_kernel<<<grid, block, 0, stream>>>(x, W, U, bias, Wd, bd, out);
}